// Round 6
// baseline (275.141 us; speedup 1.0000x reference)
//
#include <hip/hip_runtime.h>

// fp16 compute throughout (fp16 MFMA = bf16 rate on gfx950, 8x lower rounding error).
typedef _Float16 f16;
typedef __attribute__((ext_vector_type(8))) _Float16 f16x8;
typedef __attribute__((ext_vector_type(4))) _Float16 f16x4;
typedef __attribute__((ext_vector_type(4))) float   f32x4;

typedef unsigned int u32;
typedef __attribute__((address_space(1))) const u32 gu32;
typedef __attribute__((address_space(3))) u32 lu32;

// async global->LDS, 16B per lane; LDS dest = wave-uniform base + lane*16
__device__ inline void gll16(const void* g, void* l) {
  __builtin_amdgcn_global_load_lds((gu32*)g, (lu32*)l, 16, 0, 0);
}

// ---------------- prep: weight transposes (z<3) + x f32->f16 convert (z=3) ----------------
__global__ void prep(const float* __restrict__ Wq, const float* __restrict__ Wkv,
                     const float* __restrict__ Wo, const float* __restrict__ x,
                     f16* __restrict__ WqkvT, f16* __restrict__ WoT, f16* __restrict__ xb) {
  __shared__ float tile[32][33];
  int z = blockIdx.z;
  int tx = threadIdx.x, ty = threadIdx.y;   // block (32,8)
  if (z == 3) {
    size_t flat = ((size_t)(blockIdx.y * 64 + blockIdx.x) * 256 + ty * 32 + tx) * 2;
    for (int i = 0; i < 2; i++) {
      float4 v = ((const float4*)x)[flat + i];
      f16x4 r = { (f16)v.x, (f16)v.y, (f16)v.z, (f16)v.w };
      ((f16x4*)xb)[flat + i] = r;
    }
    return;
  }
  const float* src; f16* dst; int W;
  if (z == 0)      { src = Wq;  dst = WqkvT;                       W = 1024; }
  else if (z == 1) { src = Wkv; dst = WqkvT + (size_t)1024 * 1024; W = 2048; }
  else             { src = Wo;  dst = WoT;                         W = 1024; }
  int c0 = blockIdx.x * 32, r0 = blockIdx.y * 32;
  if (c0 >= W) return;
  for (int i = 0; i < 4; i++)
    tile[ty + i * 8][tx] = src[(size_t)(r0 + ty + i * 8) * W + c0 + tx];
  __syncthreads();
  for (int i = 0; i < 4; i++)
    dst[(size_t)(c0 + ty + i * 8) * 1024 + r0 + tx] = (f16)tile[tx][ty + i * 8];
}

// ---------------- GEMM1: C[M,3072] = A(M,1024) * Bt(3072,1024)^T, BK=64 ----------------
// 128x128 tile, 4 waves 2x2; rows 128B = 8 chunks, XOR swizzle pos = p ^ (row&7).
__global__ __launch_bounds__(256) void gemm1(
    const f16* __restrict__ A, const f16* __restrict__ Bt,
    f16* __restrict__ qb, f16* __restrict__ kb, f16* __restrict__ vtb) {
  const int K = 1024;
  __shared__ f16 As[128 * 64];
  __shared__ f16 Bs[128 * 64];
  int tid = threadIdx.x;
  int wave = tid >> 6, lane = tid & 63, quad = lane >> 4, l16 = lane & 15;
  int l7 = l16 & 7;
  int m0 = blockIdx.y * 128, n0 = blockIdx.x * 128;
  int wr = (wave >> 1) * 64, wc = (wave & 1) * 64;

  f32x4 acc[4][4] = {};

  int swz = ((lane & 7) ^ ((lane >> 3) & 7)) * 8;   // swizzled source chunk (f16)
  const f16* Ag = A  + (size_t)(m0 + wave * 32 + (lane >> 3)) * K + swz;
  const f16* Bg = Bt + (size_t)(n0 + wave * 32 + (lane >> 3)) * K + swz;
  f16* Asw = As + wave * 2048;   // 32 rows x 64 f16
  f16* Bsw = Bs + wave * 2048;

  for (int k0 = 0; k0 < K; k0 += 64) {
    for (int q = 0; q < 4; q++) {
      gll16(Ag + k0 + (size_t)q * 8 * K, Asw + q * 512);
      gll16(Bg + k0 + (size_t)q * 8 * K, Bsw + q * 512);
    }
    __syncthreads();
    for (int ks = 0; ks < 2; ks++) {
      int pos = ((ks * 4 + quad) ^ l7) * 8;
      f16x8 af[4], bf[4];
      for (int mt = 0; mt < 4; mt++)
        af[mt] = *(const f16x8*)&As[(wr + mt * 16 + l16) * 64 + pos];
      for (int nt = 0; nt < 4; nt++)
        bf[nt] = *(const f16x8*)&Bs[(wc + nt * 16 + l16) * 64 + pos];
      for (int mt = 0; mt < 4; mt++)
        for (int nt = 0; nt < 4; nt++)
          acc[mt][nt] = __builtin_amdgcn_mfma_f32_16x16x32_f16(af[mt], bf[nt], acc[mt][nt], 0, 0, 0);
    }
    __syncthreads();
  }

  if (n0 < 2048) {
    for (int mt = 0; mt < 4; mt++)
      for (int nt = 0; nt < 4; nt++)
        for (int r = 0; r < 4; r++) {
          int row = m0 + wr + mt * 16 + quad * 4 + r;
          int col = n0 + wc + nt * 16 + l16;
          float v = acc[mt][nt][r];
          int b = row >> 11, n = row & 2047;
          if (col < 1024) {
            // fold attention scale AND log2(e): softmax runs in log2 domain
            qb[(((size_t)b * 16 + (col >> 6)) * 2048 + n) * 64 + (col & 63)] =
                (f16)(v * 0.1803368801111137f);  // 0.125 * log2(e)
          } else {
            int c = col - 1024;
            kb[(((size_t)b * 16 + (c >> 6)) * 2048 + n) * 64 + (c & 63)] = (f16)v;
          }
        }
  } else {
    // v: blocked [bh][jblk][d][jin], packed f16x4 along n (jin)
    for (int mt = 0; mt < 4; mt++)
      for (int nt = 0; nt < 4; nt++) {
        int rb = m0 + wr + mt * 16 + quad * 4;
        int c  = n0 + wc + nt * 16 + l16 - 2048;
        int b = rb >> 11, n = rb & 2047;
        f16x4 pk = { (f16)acc[mt][nt][0], (f16)acc[mt][nt][1],
                     (f16)acc[mt][nt][2], (f16)acc[mt][nt][3] };
        size_t idx = (((size_t)(b * 16 + (c >> 6)) * 32 + (n >> 6)) * 64 + (c & 63)) * 64 + (n & 63);
        *(f16x4*)&vtb[idx] = pk;
      }
  }
}

// ---------------- GEMM2: out[M,1024] = A(M,1024)*Bt(1024,1024)^T + bo, BK=64 ----------------
__global__ __launch_bounds__(256) void gemm2(
    const f16* __restrict__ A, const f16* __restrict__ Bt,
    const float* __restrict__ bo, float* __restrict__ outf) {
  const int K = 1024;
  __shared__ f16 As[128 * 64];
  __shared__ f16 Bs[64 * 64];
  int tid = threadIdx.x;
  int wave = tid >> 6, lane = tid & 63, quad = lane >> 4, l16 = lane & 15;
  int l7 = l16 & 7;
  int m0 = blockIdx.y * 128, n0 = blockIdx.x * 64;
  int wr = (wave >> 1) * 64, wc = (wave & 1) * 32;

  f32x4 acc[4][2] = {};

  int swz = ((lane & 7) ^ ((lane >> 3) & 7)) * 8;
  const f16* Ag = A  + (size_t)(m0 + wave * 32 + (lane >> 3)) * K + swz;
  const f16* Bg = Bt + (size_t)(n0 + wave * 16 + (lane >> 3)) * K + swz;
  f16* Asw = As + wave * 2048;
  f16* Bsw = Bs + wave * 1024;   // 16 rows x 64 f16

  for (int k0 = 0; k0 < K; k0 += 64) {
    for (int q = 0; q < 4; q++)
      gll16(Ag + k0 + (size_t)q * 8 * K, Asw + q * 512);
    gll16(Bg + k0, Bsw);
    gll16(Bg + k0 + (size_t)8 * K, Bsw + 512);
    __syncthreads();
    for (int ks = 0; ks < 2; ks++) {
      int pos = ((ks * 4 + quad) ^ l7) * 8;
      f16x8 af[4], bf[2];
      for (int mt = 0; mt < 4; mt++)
        af[mt] = *(const f16x8*)&As[(wr + mt * 16 + l16) * 64 + pos];
      for (int nt = 0; nt < 2; nt++)
        bf[nt] = *(const f16x8*)&Bs[(wc + nt * 16 + l16) * 64 + pos];
      for (int mt = 0; mt < 4; mt++)
        for (int nt = 0; nt < 2; nt++)
          acc[mt][nt] = __builtin_amdgcn_mfma_f32_16x16x32_f16(af[mt], bf[nt], acc[mt][nt], 0, 0, 0);
    }
    __syncthreads();
  }

  for (int mt = 0; mt < 4; mt++)
    for (int nt = 0; nt < 2; nt++)
      for (int r = 0; r < 4; r++) {
        int row = m0 + wr + mt * 16 + quad * 4 + r;
        int col = n0 + wc + nt * 16 + l16;
        outf[(size_t)row * 1024 + col] = acc[mt][nt][r] + bo[col];
      }
}

// ---------------- attention main: split-j tasks, partial outputs ----------------
// Task = (bh, 64-row tile t in 0..31, j-chunk c of <=8 iters/512 j). Chunk boundaries
// (512) align with tile boundaries (64) -> all 4 waves live in every chunk. 2560 blocks
// (~10/CU queued, 6 resident) -> critical path 8 iters (was 32: the r5 within-CU tail).
// Each task writes partial (m, l, O^T f16) to ws; combine() merges 1-4 chunks/tile.
// gm (unmasked row-max) is only a softmax shift; cancels except via eps (<=3e-5).
__global__ __launch_bounds__(256, 6) void attn(
    const f16* __restrict__ qb, const f16* __restrict__ kb,
    const f16* __restrict__ vtb, f16* __restrict__ PO,
    float* __restrict__ PM, float* __restrict__ PL) {
  __shared__ f16 Ks[64 * 64];        // [j][d], swizzled
  __shared__ f16 Vs[64 * 64];        // [d][j], swizzled
  __shared__ f16 Ps[4][16 * 64];     // per-wave [i(16)][j(64)], swizzled
  int tid = threadIdx.x, wave = tid >> 6, lane = tid & 63, quad = lane >> 4, l16 = lane & 15;
  int l7 = l16 & 15 & 7;

  int bx = blockIdx.x;               // gridDim = 2560
  int bh = (bx & 7) * 4 + ((bx >> 3) & 3);   // XCD-pinned: 4 heads per XCD L2
  int task = bx >> 5;                // 0..79
  int t, c;
  if (task < 8)       { t = task;                          c = 0; }
  else if (task < 24) { int u = task - 8;  t = 8 + (u >> 1);  c = u & 1; }
  else if (task < 48) { int u = task - 24; t = 16 + u / 3;    c = u % 3; }
  else                { int u = task - 48; t = 24 + (u >> 2); c = u & 3; }
  int qi0 = t * 64;
  int jlo = c * 512;
  int jhi = min(jlo + 512, qi0 + 64);

  const f16* Q  = qb + (size_t)bh * 2048 * 64;
  const char* Kg = (const char*)(kb + (size_t)bh * 2048 * 64);
  const char* Vbase = (const char*)(vtb + (size_t)bh * 32 * 4096);
  int wq0 = qi0 + wave * 16;         // this wave's 16-row m-tile
  int i = wq0 + l16;                 // this lane's q-row

  f16x8 qf[2];
  for (int ks = 0; ks < 2; ks++)
    qf[ks] = *(const f16x8*)&Q[(size_t)(wq0 + l16) * 64 + ks * 32 + quad * 8];

  f32x4 acc[4] = {};
  float mrow = -1e30f, lrow = 0.f;

  int sg = ((lane & 7) ^ ((lane >> 3) & 7)) * 16;
  int jl = wave * 16 + (lane >> 3);

  for (int j0 = jlo; j0 < jhi; j0 += 64) {
    const char* kg = Kg + (size_t)j0 * 128;
    const char* vt = Vbase + (size_t)(j0 >> 6) * 8192;
    gll16(kg + (size_t)jl * 128 + sg,        (char*)Ks + wave * 2048);
    gll16(kg + (size_t)(jl + 8) * 128 + sg,  (char*)Ks + wave * 2048 + 1024);
    gll16(vt + (size_t)jl * 128 + sg,        (char*)Vs + wave * 2048);
    gll16(vt + (size_t)(jl + 8) * 128 + sg,  (char*)Vs + wave * 2048 + 1024);
    __syncthreads();

    if (j0 <= wq0 + 15) {            // wave-uniform: m-tile live for this j-block
      f16x8 kf[4][2], vf[4][2];
      for (int nt = 0; nt < 4; nt++)
        for (int ks = 0; ks < 2; ks++) {
          int pos = ((ks * 4 + quad) ^ l7) << 3;
          kf[nt][ks] = *(const f16x8*)&Ks[(nt * 16 + l16) * 64 + pos];
          vf[nt][ks] = *(const f16x8*)&Vs[(nt * 16 + l16) * 64 + pos];
        }

      // S^T tiles: lane = (j = j0+nt*16+quad*4+r, i = l16)
      f32x4 st[4];
      for (int nt = 0; nt < 4; nt++) {
        f32x4 z = {0.f, 0.f, 0.f, 0.f};
        z = __builtin_amdgcn_mfma_f32_16x16x32_f16(kf[nt][0], qf[0], z, 0, 0, 0);
        z = __builtin_amdgcn_mfma_f32_16x16x32_f16(kf[nt][1], qf[1], z, 0, 0, 0);
        st[nt] = z;
      }
      if (j0 + 63 > wq0) {           // partial block: causal mask
        for (int nt = 0; nt < 4; nt++) {
          int jc = j0 + nt * 16 + quad * 4;
          for (int rr = 0; rr < 4; rr++)
            st[nt][rr] = (jc + rr <= i) ? st[nt][rr] : -1e30f;
        }
      }
      // row max: reg tree + 2 cross-quad shuffles
      float v = fmaxf(fmaxf(fmaxf(st[0][0], st[0][1]), fmaxf(st[0][2], st[0][3])),
                      fmaxf(fmaxf(st[1][0], st[1][1]), fmaxf(st[1][2], st[1][3])));
      v = fmaxf(v, fmaxf(fmaxf(fmaxf(st[2][0], st[2][1]), fmaxf(st[2][2], st[2][3])),
                         fmaxf(fmaxf(st[3][0], st[3][1]), fmaxf(st[3][2], st[3][3]))));
      v = fmaxf(v, __shfl_xor(v, 16));
      v = fmaxf(v, __shfl_xor(v, 32));
      float mold = mrow;
      float mn = fmaxf(mold, v);
      mrow = mn;
      if (__any(mn > mold)) {        // skip rescale when no row got a new max
        float al = __builtin_amdgcn_exp2f(mold - mn);
        lrow *= al;
        for (int nt = 0; nt < 4; nt++)
          for (int rr = 0; rr < 4; rr++) acc[nt][rr] *= al;
      }
      // p = 2^(s-m) (masked entries underflow to 0); packed swizzled write to Ps[i][j]
      float psum = 0.f;
      for (int nt = 0; nt < 4; nt++) {
        f16x4 pk;
        for (int rr = 0; rr < 4; rr++) {
          float p = __builtin_amdgcn_exp2f(st[nt][rr] - mn);
          psum += p;
          pk[rr] = (f16)p;
        }
        int pos = (nt * 2 + (quad >> 1)) ^ l7;
        *(f16x4*)((char*)&Ps[wave][0] + l16 * 128 + pos * 16 + (quad & 1) * 8) = pk;
      }
      psum += __shfl_xor(psum, 16);
      psum += __shfl_xor(psum, 32);
      lrow += psum;

      // O^T += V^T P^T
      for (int ks = 0; ks < 2; ks++) {
        f16x8 pf = *(const f16x8*)((char*)&Ps[wave][0] + l16 * 128 + (((ks * 4 + quad) ^ l7) * 16));
        for (int nt = 0; nt < 4; nt++)
          acc[nt] = __builtin_amdgcn_mfma_f32_16x16x32_f16(vf[nt][ks], pf, acc[nt], 0, 0, 0);
      }
    }
    __syncthreads();
  }

  // partial epilogue: O^T (f16), m, l. acc lane = (d = nt*16+quad*4+rr, i_tile = wave*16+l16)
  size_t pb = ((size_t)bh * 80 + task) * 4096;
  int it = wave * 16 + l16;
  for (int nt = 0; nt < 4; nt++)
    for (int rr = 0; rr < 4; rr++)
      PO[pb + (size_t)(nt * 16 + quad * 4 + rr) * 64 + it] = (f16)acc[nt][rr];
  if (quad == 0) {
    PM[(size_t)(bh * 80 + task) * 64 + it] = mrow;
    PL[(size_t)(bh * 80 + task) * 64 + it] = lrow;
  }
}

// ---------------- combine: merge 1-4 chunk partials per (bh, tile), write ob ----------------
__global__ __launch_bounds__(256) void combine(
    const f16* __restrict__ PO, const float* __restrict__ PM,
    const float* __restrict__ PL, f16* __restrict__ ob) {
  int bx = blockIdx.x;               // 1024 = 32 bh x 32 tiles
  int bh = bx & 31, t = bx >> 5;
  int b = bh >> 4, h = bh & 15;
  int nc = (t + 8) >> 3;             // ceil((t+1)/8)
  int base = (t < 8) ? t : (t < 16) ? 8 + 2 * (t - 8)
           : (t < 24) ? 24 + 3 * (t - 16) : 48 + 4 * (t - 24);
  int tid = threadIdx.x;
  int i = tid & 63, dg = tid >> 6;   // i-row, d-group (16 d each)

  size_t tb = (size_t)bh * 80 + base;
  float m[4], w[4];
  float gm = -1e30f;
  for (int c = 0; c < nc; c++) { m[c] = PM[(tb + c) * 64 + i]; gm = fmaxf(gm, m[c]); }
  float l = 0.f;
  for (int c = 0; c < nc; c++) {
    w[c] = __builtin_amdgcn_exp2f(m[c] - gm);
    l += w[c] * PL[(tb + c) * 64 + i];
  }
  float inv = 1.f / (l + 1e-8f);

  float Ov[16] = {};
  for (int c = 0; c < nc; c++) {
    const f16* po = PO + (tb + c) * 4096 + (size_t)dg * 16 * 64 + i;
    float wc = w[c];
    for (int dd = 0; dd < 16; dd++)
      Ov[dd] += wc * (float)po[dd * 64];
  }
  f16* dst = &ob[((size_t)b * 2048 + t * 64 + i) * 1024 + h * 64 + dg * 16];
  for (int g = 0; g < 4; g++) {
    f16x4 o = { (f16)(Ov[g * 4] * inv), (f16)(Ov[g * 4 + 1] * inv),
                (f16)(Ov[g * 4 + 2] * inv), (f16)(Ov[g * 4 + 3] * inv) };
    *(f16x4*)&dst[g * 4] = o;
  }
}

extern "C" void kernel_launch(void* const* d_in, const int* in_sizes, int n_in,
                              void* d_out, int out_size, void* d_ws, size_t ws_size,
                              hipStream_t stream) {
  const float* x   = (const float*)d_in[0];   // (2,2048,1024)
  const float* Wq  = (const float*)d_in[1];   // (1024,1024)
  const float* Wkv = (const float*)d_in[2];   // (1024,2048)
  const float* Wo  = (const float*)d_in[3];   // (1024,1024)
  const float* bo  = (const float*)d_in[4];   // (1024,)
  float* out = (float*)d_out;                 // (2,2048,1024) f32

  char* ws = (char*)d_ws;
  f16* xb    = (f16*)ws;  ws += (size_t)4096 * 1024 * 2;
  f16* WqkvT = (f16*)ws;  ws += (size_t)3072 * 1024 * 2;
  f16* WoT   = (f16*)ws;  ws += (size_t)1024 * 1024 * 2;
  f16* qb    = (f16*)ws;  ws += (size_t)32 * 2048 * 64 * 2;
  f16* kb    = (f16*)ws;  ws += (size_t)32 * 2048 * 64 * 2;
  f16* vtb   = (f16*)ws;  ws += (size_t)32 * 64 * 2048 * 2;
  f16* PO    = (f16*)ws;  ws += (size_t)32 * 80 * 4096 * 2;   // ~21 MB partial O^T
  float* PM  = (float*)ws; ws += (size_t)32 * 80 * 64 * 4;
  float* PL  = (float*)ws; ws += (size_t)32 * 80 * 64 * 4;
  f16* ob    = xb;  // xb dead after GEMM1; reuse

  prep<<<dim3(64, 32, 4), dim3(32, 8), 0, stream>>>(Wq, Wkv, Wo, x, WqkvT, WoT, xb);
  gemm1<<<dim3(24, 32), 256, 0, stream>>>(xb, WqkvT, qb, kb, vtb);
  attn<<<dim3(2560), 256, 0, stream>>>(qb, kb, vtb, PO, PM, PL);
  combine<<<dim3(1024), 256, 0, stream>>>(PO, PM, PL, ob);
  gemm2<<<dim3(16, 32), 256, 0, stream>>>(ob, WoT, bo, out);
}

// Round 7
// 181.772 us; speedup vs baseline: 1.5137x; 1.5137x over previous
//
#include <hip/hip_runtime.h>

// fp16 compute throughout (fp16 MFMA = bf16 rate on gfx950, 8x lower rounding error).
typedef _Float16 f16;
typedef __attribute__((ext_vector_type(8))) _Float16 f16x8;
typedef __attribute__((ext_vector_type(4))) _Float16 f16x4;
typedef __attribute__((ext_vector_type(4))) float   f32x4;

typedef unsigned int u32;
typedef __attribute__((address_space(1))) const u32 gu32;
typedef __attribute__((address_space(3))) u32 lu32;

// async global->LDS, 16B per lane; LDS dest = wave-uniform base + lane*16
__device__ inline void gll16(const void* g, void* l) {
  __builtin_amdgcn_global_load_lds((gu32*)g, (lu32*)l, 16, 0, 0);
}

// ---------------- prep: weight transposes (z<3) + x f32->f16 convert (z=3) ----------------
__global__ void prep(const float* __restrict__ Wq, const float* __restrict__ Wkv,
                     const float* __restrict__ Wo, const float* __restrict__ x,
                     f16* __restrict__ WqkvT, f16* __restrict__ WoT, f16* __restrict__ xb) {
  __shared__ float tile[32][33];
  int z = blockIdx.z;
  int tx = threadIdx.x, ty = threadIdx.y;   // block (32,8)
  if (z == 3) {
    size_t flat = ((size_t)(blockIdx.y * 64 + blockIdx.x) * 256 + ty * 32 + tx) * 2;
    for (int i = 0; i < 2; i++) {
      float4 v = ((const float4*)x)[flat + i];
      f16x4 r = { (f16)v.x, (f16)v.y, (f16)v.z, (f16)v.w };
      ((f16x4*)xb)[flat + i] = r;
    }
    return;
  }
  const float* src; f16* dst; int W;
  if (z == 0)      { src = Wq;  dst = WqkvT;                       W = 1024; }
  else if (z == 1) { src = Wkv; dst = WqkvT + (size_t)1024 * 1024; W = 2048; }
  else             { src = Wo;  dst = WoT;                         W = 1024; }
  int c0 = blockIdx.x * 32, r0 = blockIdx.y * 32;
  if (c0 >= W) return;
  for (int i = 0; i < 4; i++)
    tile[ty + i * 8][tx] = src[(size_t)(r0 + ty + i * 8) * W + c0 + tx];
  __syncthreads();
  for (int i = 0; i < 4; i++)
    dst[(size_t)(c0 + ty + i * 8) * 1024 + r0 + tx] = (f16)tile[tx][ty + i * 8];
}

// ---------------- GEMM1: C[M,3072] = A(M,1024) * Bt(3072,1024)^T (r5-proven) ----------------
__global__ __launch_bounds__(256) void gemm1(
    const f16* __restrict__ A, const f16* __restrict__ Bt,
    f16* __restrict__ qb, f16* __restrict__ kb, f16* __restrict__ vtb) {
  const int K = 1024;
  __shared__ f16 As[128 * 32];
  __shared__ f16 Bs[128 * 32];
  int tid = threadIdx.x;
  int wave = tid >> 6, lane = tid & 63, quad = lane >> 4, l16 = lane & 15;
  int m0 = blockIdx.y * 128, n0 = blockIdx.x * 128;
  int wr = (wave >> 1) * 64, wc = (wave & 1) * 64;

  f32x4 acc[4][4] = {};

  int gA = (((lane & 3) ^ ((lane >> 3) & 3))) * 8;   // swizzled source k-chunk
  const f16* Ag = A  + (size_t)(m0 + wave * 32 + (lane >> 2)) * K + gA;
  const f16* Bg = Bt + (size_t)(n0 + wave * 32 + (lane >> 2)) * K + gA;
  f16* Asw = As + wave * 1024;
  f16* Bsw = Bs + wave * 1024;
  int rsz = (l16 >> 1) & 3;

  for (int k0 = 0; k0 < K; k0 += 32) {
    gll16(Ag + k0, Asw);
    gll16(Ag + (size_t)16 * K + k0, Asw + 512);
    gll16(Bg + k0, Bsw);
    gll16(Bg + (size_t)16 * K + k0, Bsw + 512);
    __syncthreads();
    f16x8 af[4], bf[4];
    for (int mt = 0; mt < 4; mt++)
      af[mt] = *(const f16x8*)&As[(wr + mt * 16 + l16) * 32 + ((quad ^ rsz) << 3)];
    for (int nt = 0; nt < 4; nt++)
      bf[nt] = *(const f16x8*)&Bs[(wc + nt * 16 + l16) * 32 + ((quad ^ rsz) << 3)];
    for (int mt = 0; mt < 4; mt++)
      for (int nt = 0; nt < 4; nt++)
        acc[mt][nt] = __builtin_amdgcn_mfma_f32_16x16x32_f16(af[mt], bf[nt], acc[mt][nt], 0, 0, 0);
    __syncthreads();
  }

  if (n0 < 2048) {
    for (int mt = 0; mt < 4; mt++)
      for (int nt = 0; nt < 4; nt++)
        for (int r = 0; r < 4; r++) {
          int row = m0 + wr + mt * 16 + quad * 4 + r;
          int col = n0 + wc + nt * 16 + l16;
          float v = acc[mt][nt][r];
          int b = row >> 11, n = row & 2047;
          if (col < 1024) {
            // fold attention scale AND log2(e): softmax runs in log2 domain
            qb[(((size_t)b * 16 + (col >> 6)) * 2048 + n) * 64 + (col & 63)] =
                (f16)(v * 0.1803368801111137f);  // 0.125 * log2(e)
          } else {
            int c = col - 1024;
            kb[(((size_t)b * 16 + (c >> 6)) * 2048 + n) * 64 + (c & 63)] = (f16)v;
          }
        }
  } else {
    // v: blocked [bh][jblk][d][jin], packed f16x4 along n (jin)
    for (int mt = 0; mt < 4; mt++)
      for (int nt = 0; nt < 4; nt++) {
        int rb = m0 + wr + mt * 16 + quad * 4;
        int c  = n0 + wc + nt * 16 + l16 - 2048;
        int b = rb >> 11, n = rb & 2047;
        f16x4 pk = { (f16)acc[mt][nt][0], (f16)acc[mt][nt][1],
                     (f16)acc[mt][nt][2], (f16)acc[mt][nt][3] };
        size_t idx = (((size_t)(b * 16 + (c >> 6)) * 32 + (n >> 6)) * 64 + (c & 63)) * 64 + (n & 63);
        *(f16x4*)&vtb[idx] = pk;
      }
  }
}

// ---------------- GEMM2: out[M,1024] = A(M,1024)*Bt(1024,1024)^T + bo (r5-proven) ----------------
__global__ __launch_bounds__(256) void gemm2(
    const f16* __restrict__ A, const f16* __restrict__ Bt,
    const float* __restrict__ bo, float* __restrict__ outf) {
  const int K = 1024;
  __shared__ f16 As[128 * 32];
  __shared__ f16 Bs[64 * 32];
  int tid = threadIdx.x;
  int wave = tid >> 6, lane = tid & 63, quad = lane >> 4, l16 = lane & 15;
  int m0 = blockIdx.y * 128, n0 = blockIdx.x * 64;
  int wr = (wave >> 1) * 64, wc = (wave & 1) * 32;

  f32x4 acc[4][2] = {};

  int gA = (((lane & 3) ^ ((lane >> 3) & 3))) * 8;
  const f16* Ag = A  + (size_t)(m0 + wave * 32 + (lane >> 2)) * K + gA;
  const f16* Bg = Bt + (size_t)(n0 + wave * 16 + (lane >> 2)) * K + gA;
  f16* Asw = As + wave * 1024;
  f16* Bsw = Bs + wave * 512;
  int rsz = (l16 >> 1) & 3;

  for (int k0 = 0; k0 < K; k0 += 32) {
    gll16(Ag + k0, Asw);
    gll16(Ag + (size_t)16 * K + k0, Asw + 512);
    gll16(Bg + k0, Bsw);
    __syncthreads();
    f16x8 af[4], bf[2];
    for (int mt = 0; mt < 4; mt++)
      af[mt] = *(const f16x8*)&As[(wr + mt * 16 + l16) * 32 + ((quad ^ rsz) << 3)];
    for (int nt = 0; nt < 2; nt++)
      bf[nt] = *(const f16x8*)&Bs[(wc + nt * 16 + l16) * 32 + ((quad ^ rsz) << 3)];
    for (int mt = 0; mt < 4; mt++)
      for (int nt = 0; nt < 2; nt++)
        acc[mt][nt] = __builtin_amdgcn_mfma_f32_16x16x32_f16(af[mt], bf[nt], acc[mt][nt], 0, 0, 0);
    __syncthreads();
  }

  for (int mt = 0; mt < 4; mt++)
    for (int nt = 0; nt < 2; nt++)
      for (int r = 0; r < 4; r++) {
        int row = m0 + wr + mt * 16 + quad * 4 + r;
        int col = n0 + wc + nt * 16 + l16;
        outf[(size_t)row * 1024 + col] = acc[mt][nt][r] + bo[col];
      }
}

// ---------------- fused causal attention: intra-block split-j, LDS merge ----------------
// Block = (bh, 64-row tile t). Wave w owns the w-th quarter of the T=t+1 j-blocks and
// processes ALL 4 m-tiles against its PRIVATE 16KB K/V stage -> j-loop has NO barriers
// (explicit s_waitcnt vmcnt(8)/vmcnt(0) orders DMA vs frag reads; next-iter DMA can't
// clobber in-flight ds_reads because MFMA consumption drains lgkm before the DMA issues).
// Critical path: ceil(T/4) <= 8 iters (r5's t=31 block was 32 serial barrier-gated iters).
// Merge of the 4 wave-partials (m, l, f16 O — r6 proved f16 partials cost nothing) is
// done in LDS with 1 barrier (r6's HBM partials caused 15x write amplification — never again).
// Per-CU balance: t set {s,15-s,16+s,31-s} -> ceil-cost sum = 18 for every s.
// gm (unmasked row-max) is only a softmax shift; cancels except via eps (<=3e-5).
__global__ __launch_bounds__(256, 2) void attn(
    const f16* __restrict__ qb, const f16* __restrict__ kb,
    const f16* __restrict__ vtb, f16* __restrict__ ob) {
  __shared__ __align__(16) char SMEM[75776];  // 4x16KB stage(+O-merge reuse) + 4x2KB Ps + m/l
  int tid = threadIdx.x, wave = tid >> 6, lane = tid & 63, quad = lane >> 4, l16 = lane & 15;
  int l7 = l16 & 7;

  int bx = blockIdx.x;               // gridDim = 1024
  int q = bx >> 8, r = bx & 255;
  int xcd = r & 7, idx = r >> 3;
  int bh = xcd * 4 + (idx & 3);      // 4 heads per XCD L2 (proven 12MB FETCH)
  int srem = idx >> 2;               // 0..7
  int t = (q == 0) ? srem : (q == 1) ? 15 - srem : (q == 2) ? 16 + srem : 31 - srem;
  int qi0 = t * 64;
  int b = bh >> 4, h = bh & 15;
  int T = t + 1, C = (T + 3) >> 2;   // wave chunk length in 64-j blocks

  const f16* Q  = qb + (size_t)bh * 2048 * 64;
  const char* Kg = (const char*)(kb + (size_t)bh * 2048 * 64);
  const char* Vbase = (const char*)(vtb + (size_t)bh * 32 * 4096);

  f16* Kw = (f16*)(SMEM + wave * 16384);          // [j(64)][d(64)] swizzled
  f16* Vw = Kw + 4096;                            // [d(64)][j(64)] swizzled
  f16* Pw = (f16*)(SMEM + 65536 + wave * 2048);   // [i(16)][j(64)] swizzled
  float* Msp = (float*)(SMEM + 73728);            // [w][64]
  float* Lsp = (float*)(SMEM + 74752);            // [w][64]

  f16x8 qf[4][2];
  for (int mt = 0; mt < 4; mt++)
    for (int ks = 0; ks < 2; ks++)
      qf[mt][ks] = *(const f16x8*)&Q[(size_t)(qi0 + mt * 16 + l16) * 64 + ks * 32 + quad * 8];

  f32x4 acc[4][4] = {};
  float mrow[4], lrow[4];
  for (int mt = 0; mt < 4; mt++) { mrow[mt] = -1e30f; lrow[mt] = 0.f; }

  // staging swizzle: 16B chunk (row, pos lane&7) holds global chunk (lane&7)^(row&7)
  int sg = ((lane & 7) ^ ((lane >> 3) & 7)) * 16;

  for (int n = 0; n < C; n++) {
    int jb = wave * C + n;
    if (jb >= T) break;              // wave-private loop: no barriers, early exit ok
    int j0 = jb * 64;
    const char* kg = Kg + (size_t)j0 * 128;
    const char* vt = Vbase + (size_t)(j0 >> 6) * 8192;
    for (int qq = 0; qq < 8; qq++)
      gll16(kg + (size_t)(qq * 8 + (lane >> 3)) * 128 + sg, (char*)Kw + qq * 1024);
    for (int qq = 0; qq < 8; qq++)
      gll16(vt + (size_t)(qq * 8 + (lane >> 3)) * 128 + sg, (char*)Vw + qq * 1024);

    __builtin_amdgcn_s_waitcnt(0x0F78);   // vmcnt(8): K landed, V still in flight
    f16x8 kf[4][2];
    for (int nt = 0; nt < 4; nt++)
      for (int ks = 0; ks < 2; ks++)
        kf[nt][ks] = *(const f16x8*)&Kw[(nt * 16 + l16) * 64 + (((ks * 4 + quad) ^ l7) << 3)];
    __builtin_amdgcn_s_waitcnt(0x0F70);   // vmcnt(0): V landed
    f16x8 vf[4][2];
    for (int nt = 0; nt < 4; nt++)
      for (int ks = 0; ks < 2; ks++)
        vf[nt][ks] = *(const f16x8*)&Vw[(nt * 16 + l16) * 64 + (((ks * 4 + quad) ^ l7) << 3)];

    bool last = (j0 == qi0);              // only j-block that needs the causal mask
    for (int mt = 0; mt < 4; mt++) {
      int i = qi0 + mt * 16 + l16;        // this lane's q-row

      // S^T tiles: lane = (j = j0+nt*16+quad*4+rr, i = l16)
      f32x4 st[4];
      for (int nt = 0; nt < 4; nt++) {
        f32x4 z = {0.f, 0.f, 0.f, 0.f};
        z = __builtin_amdgcn_mfma_f32_16x16x32_f16(kf[nt][0], qf[mt][0], z, 0, 0, 0);
        z = __builtin_amdgcn_mfma_f32_16x16x32_f16(kf[nt][1], qf[mt][1], z, 0, 0, 0);
        st[nt] = z;
      }
      if (last) {
        for (int nt = 0; nt < 4; nt++) {
          int jc = j0 + nt * 16 + quad * 4;
          for (int rr = 0; rr < 4; rr++)
            st[nt][rr] = (jc + rr <= i) ? st[nt][rr] : -1e30f;
        }
      }
      // row max: reg tree + 2 cross-quad shuffles
      float v = fmaxf(fmaxf(fmaxf(st[0][0], st[0][1]), fmaxf(st[0][2], st[0][3])),
                      fmaxf(fmaxf(st[1][0], st[1][1]), fmaxf(st[1][2], st[1][3])));
      v = fmaxf(v, fmaxf(fmaxf(fmaxf(st[2][0], st[2][1]), fmaxf(st[2][2], st[2][3])),
                         fmaxf(fmaxf(st[3][0], st[3][1]), fmaxf(st[3][2], st[3][3]))));
      v = fmaxf(v, __shfl_xor(v, 16));
      v = fmaxf(v, __shfl_xor(v, 32));
      float mold = mrow[mt];
      float mn = fmaxf(mold, v);
      mrow[mt] = mn;
      if (__any(mn > mold)) {             // skip rescale when no row got a new max
        float al = __builtin_amdgcn_exp2f(mold - mn);
        lrow[mt] *= al;
        for (int nt = 0; nt < 4; nt++)
          for (int rr = 0; rr < 4; rr++) acc[mt][nt][rr] *= al;
      }
      // p = 2^(s-m) (masked entries underflow to 0); packed swizzled write to Pw[i][j]
      float psum = 0.f;
      for (int nt = 0; nt < 4; nt++) {
        f16x4 pk;
        for (int rr = 0; rr < 4; rr++) {
          float p = __builtin_amdgcn_exp2f(st[nt][rr] - mn);
          psum += p;
          pk[rr] = (f16)p;
        }
        int pos = (nt * 2 + (quad >> 1)) ^ l7;
        *(f16x4*)((char*)Pw + l16 * 128 + pos * 16 + (quad & 1) * 8) = pk;
      }
      psum += __shfl_xor(psum, 16);
      psum += __shfl_xor(psum, 32);
      lrow[mt] += psum;

      // O^T += V^T P^T
      for (int ks = 0; ks < 2; ks++) {
        f16x8 pf = *(const f16x8*)((char*)Pw + l16 * 128 + (((ks * 4 + quad) ^ l7) * 16));
        for (int nt = 0; nt < 4; nt++)
          acc[mt][nt] = __builtin_amdgcn_mfma_f32_16x16x32_f16(vf[nt][ks], pf, acc[mt][nt], 0, 0, 0);
      }
    }
  }

  // write this wave's partials: O (f16, [i(64)][d(64)] pad 72) into own stage region, m/l
  f16* Ow = (f16*)(SMEM + wave * 16384);
  for (int mt = 0; mt < 4; mt++)
    for (int nt = 0; nt < 4; nt++) {
      f16x4 pk = { (f16)acc[mt][nt][0], (f16)acc[mt][nt][1],
                   (f16)acc[mt][nt][2], (f16)acc[mt][nt][3] };
      *(f16x4*)((char*)Ow + (mt * 16 + l16) * 144 + (nt * 16 + quad * 4) * 2) = pk;
    }
  if (quad == 0)
    for (int mt = 0; mt < 4; mt++) {
      Msp[wave * 64 + mt * 16 + l16] = mrow[mt];
      Lsp[wave * 64 + mt * 16 + l16] = lrow[mt];
    }
  __syncthreads();

  // merge 4 wave-partials; thread -> (i0 = tid>>2, d range (tid&3)*16 .. +15)
  int i0 = tid >> 2, db = (tid & 3) * 16;
  float mw[4], ww[4];
  float gm = -1e30f;
  for (int w = 0; w < 4; w++) { mw[w] = Msp[w * 64 + i0]; gm = fmaxf(gm, mw[w]); }
  float l = 0.f;
  for (int w = 0; w < 4; w++) {
    ww[w] = __builtin_amdgcn_exp2f(mw[w] - gm);
    l += ww[w] * Lsp[w * 64 + i0];
  }
  float inv = 1.f / (l + 1e-8f);
  float Ov[16] = {};
  for (int w = 0; w < 4; w++) {
    const f16* Op = (const f16*)((char*)SMEM + w * 16384 + i0 * 144 + db * 2);
    f16x8 a = *(const f16x8*)Op;
    f16x8 c = *(const f16x8*)(Op + 8);
    float wc = ww[w];
    for (int dd = 0; dd < 8; dd++) { Ov[dd] += wc * (float)a[dd]; Ov[8 + dd] += wc * (float)c[dd]; }
  }
  f16* dst = &ob[((size_t)b * 2048 + qi0 + i0) * 1024 + h * 64 + db];
  f16x8 o1, o2;
  for (int dd = 0; dd < 8; dd++) { o1[dd] = (f16)(Ov[dd] * inv); o2[dd] = (f16)(Ov[8 + dd] * inv); }
  *(f16x8*)dst = o1;
  *(f16x8*)(dst + 8) = o2;
}

extern "C" void kernel_launch(void* const* d_in, const int* in_sizes, int n_in,
                              void* d_out, int out_size, void* d_ws, size_t ws_size,
                              hipStream_t stream) {
  const float* x   = (const float*)d_in[0];   // (2,2048,1024)
  const float* Wq  = (const float*)d_in[1];   // (1024,1024)
  const float* Wkv = (const float*)d_in[2];   // (1024,2048)
  const float* Wo  = (const float*)d_in[3];   // (1024,1024)
  const float* bo  = (const float*)d_in[4];   // (1024,)
  float* out = (float*)d_out;                 // (2,2048,1024) f32

  char* ws = (char*)d_ws;
  f16* xb    = (f16*)ws;  ws += (size_t)4096 * 1024 * 2;
  f16* WqkvT = (f16*)ws;  ws += (size_t)3072 * 1024 * 2;
  f16* WoT   = (f16*)ws;  ws += (size_t)1024 * 1024 * 2;
  f16* qb    = (f16*)ws;  ws += (size_t)32 * 2048 * 64 * 2;
  f16* kb    = (f16*)ws;  ws += (size_t)32 * 2048 * 64 * 2;
  f16* vtb   = (f16*)ws;  ws += (size_t)32 * 64 * 2048 * 2;
  f16* ob    = xb;  // xb dead after GEMM1; reuse

  prep<<<dim3(64, 32, 4), dim3(32, 8), 0, stream>>>(Wq, Wkv, Wo, x, WqkvT, WoT, xb);
  gemm1<<<dim3(24, 32), 256, 0, stream>>>(xb, WqkvT, qb, kb, vtb);
  attn<<<dim3(1024), 256, 0, stream>>>(qb, kb, vtb, ob);
  gemm2<<<dim3(16, 32), 256, 0, stream>>>(ob, WoT, bo, out);
}